// Round 2
// baseline (290.292 us; speedup 1.0000x reference)
//
#include <hip/hip_runtime.h>

#define BLOCK 256
#define GRID 2048

__device__ __forceinline__ int argmax8(float4 a, float4 b) {
    // first-occurrence argmax over 8 (matches jnp.argmax tie-break)
    float m = a.x; int idx = 0;
    if (a.y > m) { m = a.y; idx = 1; }
    if (a.z > m) { m = a.z; idx = 2; }
    if (a.w > m) { m = a.w; idx = 3; }
    if (b.x > m) { m = b.x; idx = 4; }
    if (b.y > m) { m = b.y; idx = 5; }
    if (b.z > m) { m = b.z; idx = 6; }
    if (b.w > m) { m = b.w; idx = 7; }
    return idx;
}

__device__ __forceinline__ int group_of(int c) {
    // classes 0..2 -> 0, 3..5 -> 1, 6..7 -> 2 (branchless)
    return (int)(c >= 3) + (int)(c >= 6);
}

__global__ __launch_bounds__(BLOCK) void path_loss_fused(
    const float* __restrict__ preds,
    const int* __restrict__ targets,
    unsigned int* __restrict__ ctrs,   // ctrs[0]=mismatch count, ctrs[1]=blocks done
    float* __restrict__ out,
    int batch) {
    int tid = blockIdx.x * BLOCK + threadIdx.x;
    const int nthreads = GRID * BLOCK;
    unsigned int local = 0;
    // 2 rows per thread per iteration: int2 target load, 4x float4 pred loads
    for (int base = tid * 2; base < batch; base += nthreads * 2) {
        const float4* p = reinterpret_cast<const float4*>(preds + (size_t)base * 8);
        float4 a0 = p[0], b0 = p[1];
        float4 a1 = p[2], b1 = p[3];
        int2 t = *reinterpret_cast<const int2*>(targets + base);
        local += (unsigned int)(group_of(argmax8(a0, b0)) != group_of(t.x));
        local += (unsigned int)(group_of(argmax8(a1, b1)) != group_of(t.y));
    }
    // wave64 reduce
    #pragma unroll
    for (int off = 32; off > 0; off >>= 1)
        local += __shfl_down(local, off, 64);
    __shared__ unsigned int lds[BLOCK / 64];
    int lane = threadIdx.x & 63;
    int wave = threadIdx.x >> 6;
    if (lane == 0) lds[wave] = local;
    __syncthreads();
    if (threadIdx.x == 0) {
        unsigned int s = 0;
        #pragma unroll
        for (int i = 0; i < BLOCK / 64; ++i) s += lds[i];
        atomicAdd(&ctrs[0], s);
        __threadfence();
        unsigned int done = atomicAdd(&ctrs[1], 1u);
        if (done == (unsigned int)(gridDim.x - 1)) {
            // all block sums are visible (atomic chain + threadfence ordering)
            unsigned int total = atomicAdd(&ctrs[0], 0u);
            out[0] = (float)((double)total / (double)batch);
        }
    }
}

extern "C" void kernel_launch(void* const* d_in, const int* in_sizes, int n_in,
                              void* d_out, int out_size, void* d_ws, size_t ws_size,
                              hipStream_t stream) {
    const float* preds = (const float*)d_in[0];
    const int* targets = (const int*)d_in[1];
    int batch = in_sizes[1];  // 4194304 rows
    unsigned int* ctrs = (unsigned int*)d_ws;

    hipMemsetAsync(ctrs, 0, 2 * sizeof(unsigned int), stream);
    path_loss_fused<<<GRID, BLOCK, 0, stream>>>(preds, targets, ctrs, (float*)d_out, batch);
}

// Round 3
// 201.363 us; speedup vs baseline: 1.4416x; 1.4416x over previous
//
#include <hip/hip_runtime.h>

#define BLOCK 256
#define GRID 2048
// nthreads = 524288; batch = 4194304 -> 8 rows/thread; unroll x2 -> 4 outer iters

__device__ __forceinline__ int argmax8(float4 a, float4 b) {
    // first-occurrence argmax over 8 (matches jnp.argmax tie-break)
    float m = a.x; int idx = 0;
    if (a.y > m) { m = a.y; idx = 1; }
    if (a.z > m) { m = a.z; idx = 2; }
    if (a.w > m) { m = a.w; idx = 3; }
    if (b.x > m) { m = b.x; idx = 4; }
    if (b.y > m) { m = b.y; idx = 5; }
    if (b.z > m) { m = b.z; idx = 6; }
    if (b.w > m) { m = b.w; idx = 7; }
    return idx;
}

__device__ __forceinline__ int group_of(int c) {
    // classes 0..2 -> 0, 3..5 -> 1, 6..7 -> 2 (branchless)
    return (int)(c >= 3) + (int)(c >= 6);
}

__global__ __launch_bounds__(BLOCK) void path_loss_partial(
    const float* __restrict__ preds,
    const int* __restrict__ targets,
    unsigned int* __restrict__ partial,
    int batch) {
    const int tid = blockIdx.x * BLOCK + threadIdx.x;
    const int stride = GRID * BLOCK;
    unsigned int local = 0;
    for (int row = tid; row < batch; row += 2 * stride) {
        const int row2 = row + stride;
        const bool ok2 = row2 < batch;
        // issue all loads for both rows before any dependent compute (MLP)
        const float4* p0 = reinterpret_cast<const float4*>(preds) + (size_t)row * 2;
        float4 a0 = p0[0], b0 = p0[1];
        int t0 = targets[row];
        float4 a1 = a0, b1 = b0;
        int t1 = 0;
        if (ok2) {
            const float4* p1 = reinterpret_cast<const float4*>(preds) + (size_t)row2 * 2;
            a1 = p1[0]; b1 = p1[1];
            t1 = targets[row2];
        }
        local += (unsigned int)(group_of(argmax8(a0, b0)) != group_of(t0));
        if (ok2)
            local += (unsigned int)(group_of(argmax8(a1, b1)) != group_of(t1));
    }
    // wave64 reduce
    #pragma unroll
    for (int off = 32; off > 0; off >>= 1)
        local += __shfl_down(local, off, 64);
    __shared__ unsigned int lds[BLOCK / 64];
    const int lane = threadIdx.x & 63;
    const int wave = threadIdx.x >> 6;
    if (lane == 0) lds[wave] = local;
    __syncthreads();
    if (threadIdx.x == 0) {
        unsigned int s = 0;
        #pragma unroll
        for (int i = 0; i < BLOCK / 64; ++i) s += lds[i];
        partial[blockIdx.x] = s;   // plain store — no atomics, no fence, no init needed
    }
}

__global__ __launch_bounds__(256) void path_loss_final(
    const unsigned int* __restrict__ partial,
    float* __restrict__ out,
    int batch) {
    unsigned int local = 0;
    for (int i = threadIdx.x; i < GRID; i += 256)
        local += partial[i];
    #pragma unroll
    for (int off = 32; off > 0; off >>= 1)
        local += __shfl_down(local, off, 64);
    __shared__ unsigned int lds[4];
    const int lane = threadIdx.x & 63;
    const int wave = threadIdx.x >> 6;
    if (lane == 0) lds[wave] = local;
    __syncthreads();
    if (threadIdx.x == 0) {
        unsigned int total = lds[0] + lds[1] + lds[2] + lds[3];
        out[0] = (float)((double)total / (double)batch);
    }
}

extern "C" void kernel_launch(void* const* d_in, const int* in_sizes, int n_in,
                              void* d_out, int out_size, void* d_ws, size_t ws_size,
                              hipStream_t stream) {
    const float* preds = (const float*)d_in[0];
    const int* targets = (const int*)d_in[1];
    int batch = in_sizes[1];  // 4194304 rows
    unsigned int* partial = (unsigned int*)d_ws;

    path_loss_partial<<<GRID, BLOCK, 0, stream>>>(preds, targets, partial, batch);
    path_loss_final<<<1, 256, 0, stream>>>(partial, (float*)d_out, batch);
}

// Round 4
// 201.038 us; speedup vs baseline: 1.4440x; 1.0016x over previous
//
#include <hip/hip_runtime.h>

#define BLOCK 256
#define GRID 8192
// nthreads = 2097152; batch = 4194304 -> exactly 2 rows/thread (stride pattern)

__device__ __forceinline__ int argmax8(float4 a, float4 b) {
    // first-occurrence argmax over 8 (matches jnp.argmax tie-break)
    float m = a.x; int idx = 0;
    if (a.y > m) { m = a.y; idx = 1; }
    if (a.z > m) { m = a.z; idx = 2; }
    if (a.w > m) { m = a.w; idx = 3; }
    if (b.x > m) { m = b.x; idx = 4; }
    if (b.y > m) { m = b.y; idx = 5; }
    if (b.z > m) { m = b.z; idx = 6; }
    if (b.w > m) { m = b.w; idx = 7; }
    return idx;
}

__device__ __forceinline__ int group_of(int c) {
    // classes 0..2 -> 0, 3..5 -> 1, 6..7 -> 2 (branchless)
    return (int)(c >= 3) + (int)(c >= 6);
}

__global__ __launch_bounds__(BLOCK) void path_loss_partial(
    const float* __restrict__ preds,
    const int* __restrict__ targets,
    unsigned int* __restrict__ partial,
    int batch) {
    const int tid = blockIdx.x * BLOCK + threadIdx.x;
    const int stride = GRID * BLOCK;
    unsigned int local = 0;

    const int r0 = tid;
    const int r1 = tid + stride;
    const bool ok0 = r0 < batch;
    const bool ok1 = r1 < batch;

    // issue all loads before any dependent compute (MLP)
    float4 a0, b0, a1, b1;
    int t0 = 0, t1 = 0;
    if (ok0) {
        const float4* p0 = reinterpret_cast<const float4*>(preds) + (size_t)r0 * 2;
        a0 = p0[0]; b0 = p0[1];
        t0 = targets[r0];
    }
    if (ok1) {
        const float4* p1 = reinterpret_cast<const float4*>(preds) + (size_t)r1 * 2;
        a1 = p1[0]; b1 = p1[1];
        t1 = targets[r1];
    }
    if (ok0) local += (unsigned int)(group_of(argmax8(a0, b0)) != group_of(t0));
    if (ok1) local += (unsigned int)(group_of(argmax8(a1, b1)) != group_of(t1));

    // handle batch > GRID*BLOCK*2 (generality; not taken at B=4194304)
    for (int row = tid + 2 * stride; row < batch; row += stride) {
        const float4* p = reinterpret_cast<const float4*>(preds) + (size_t)row * 2;
        float4 a = p[0], b = p[1];
        int t = targets[row];
        local += (unsigned int)(group_of(argmax8(a, b)) != group_of(t));
    }

    // wave64 reduce
    #pragma unroll
    for (int off = 32; off > 0; off >>= 1)
        local += __shfl_down(local, off, 64);
    __shared__ unsigned int lds[BLOCK / 64];
    const int lane = threadIdx.x & 63;
    const int wave = threadIdx.x >> 6;
    if (lane == 0) lds[wave] = local;
    __syncthreads();
    if (threadIdx.x == 0) {
        unsigned int s = 0;
        #pragma unroll
        for (int i = 0; i < BLOCK / 64; ++i) s += lds[i];
        partial[blockIdx.x] = s;   // plain store — no atomics, no fence, no init needed
    }
}

__global__ __launch_bounds__(1024) void path_loss_final(
    const unsigned int* __restrict__ partial,
    float* __restrict__ out,
    int batch) {
    unsigned int local = 0;
    for (int i = threadIdx.x; i < GRID; i += 1024)
        local += partial[i];
    #pragma unroll
    for (int off = 32; off > 0; off >>= 1)
        local += __shfl_down(local, off, 64);
    __shared__ unsigned int lds[16];
    const int lane = threadIdx.x & 63;
    const int wave = threadIdx.x >> 6;
    if (lane == 0) lds[wave] = local;
    __syncthreads();
    if (threadIdx.x == 0) {
        unsigned int total = 0;
        #pragma unroll
        for (int i = 0; i < 16; ++i) total += lds[i];
        out[0] = (float)((double)total / (double)batch);
    }
}

extern "C" void kernel_launch(void* const* d_in, const int* in_sizes, int n_in,
                              void* d_out, int out_size, void* d_ws, size_t ws_size,
                              hipStream_t stream) {
    const float* preds = (const float*)d_in[0];
    const int* targets = (const int*)d_in[1];
    int batch = in_sizes[1];  // 4194304 rows
    unsigned int* partial = (unsigned int*)d_ws;

    path_loss_partial<<<GRID, BLOCK, 0, stream>>>(preds, targets, partial, batch);
    path_loss_final<<<1, 1024, 0, stream>>>(partial, (float*)d_out, batch);
}

// Round 5
// 198.843 us; speedup vs baseline: 1.4599x; 1.0110x over previous
//
#include <hip/hip_runtime.h>

#define BLOCK 256
#define GRID 8192
#define NTHREADS (GRID * BLOCK)   // 2,097,152 threads; 4 half-rows each = 4,194,304 rows

__device__ __forceinline__ int group_of(int c) {
    // classes 0..2 -> 0, 3..5 -> 1, 6..7 -> 2 (branchless)
    return (int)(c >= 3) + (int)(c >= 6);
}

__global__ __launch_bounds__(BLOCK) void path_loss_partial(
    const float* __restrict__ preds,
    const int* __restrict__ targets,
    unsigned int* __restrict__ partial,
    int batch) {
    const int tid = blockIdx.x * BLOCK + threadIdx.x;
    const int half_base = (threadIdx.x & 1) * 4;       // my half covers classes [half_base, half_base+3]
    const unsigned int keep = (threadIdx.x & 1) ^ 1;   // only even lane of each pair accumulates
    const int nhalves = batch * 2;
    unsigned int local = 0;

    #pragma unroll
    for (int k = 0; k < 4; ++k) {
        const int h = tid + k * NTHREADS;              // half-row index; 16 B/lane, fully contiguous
        if (h < nhalves) {
            const float4 v = reinterpret_cast<const float4*>(preds)[h];
            const int r = h >> 1;
            // local argmax over my 4 values, first occurrence
            float m = fmaxf(fmaxf(v.x, v.y), fmaxf(v.z, v.w));
            int idx;
            if (v.x == m)      idx = half_base + 0;
            else if (v.y == m) idx = half_base + 1;
            else if (v.z == m) idx = half_base + 2;
            else               idx = half_base + 3;
            // combine with partner half (lane^1); tie -> smaller class index (jnp.argmax)
            float m_o  = __shfl_xor(m, 1, 64);
            int   idx_o = __shfl_xor(idx, 1, 64);
            bool take_o = (m_o > m) || ((m_o == m) && (idx_o < idx));
            int ib = take_o ? idx_o : idx;
            int t = targets[r];                        // pair reads same address (broadcast)
            local += keep & (unsigned int)(group_of(ib) != group_of(t));
        }
    }

    // wave64 reduce
    #pragma unroll
    for (int off = 32; off > 0; off >>= 1)
        local += __shfl_down(local, off, 64);
    __shared__ unsigned int lds[BLOCK / 64];
    const int lane = threadIdx.x & 63;
    const int wave = threadIdx.x >> 6;
    if (lane == 0) lds[wave] = local;
    __syncthreads();
    if (threadIdx.x == 0) {
        unsigned int s = 0;
        #pragma unroll
        for (int i = 0; i < BLOCK / 64; ++i) s += lds[i];
        partial[blockIdx.x] = s;   // plain store — no atomics, no fence, no init needed
    }
}

__global__ __launch_bounds__(1024) void path_loss_final(
    const unsigned int* __restrict__ partial,
    float* __restrict__ out,
    int batch) {
    unsigned int local = 0;
    for (int i = threadIdx.x; i < GRID; i += 1024)
        local += partial[i];
    #pragma unroll
    for (int off = 32; off > 0; off >>= 1)
        local += __shfl_down(local, off, 64);
    __shared__ unsigned int lds[16];
    const int lane = threadIdx.x & 63;
    const int wave = threadIdx.x >> 6;
    if (lane == 0) lds[wave] = local;
    __syncthreads();
    if (threadIdx.x == 0) {
        unsigned int total = 0;
        #pragma unroll
        for (int i = 0; i < 16; ++i) total += lds[i];
        out[0] = (float)((double)total / (double)batch);
    }
}

extern "C" void kernel_launch(void* const* d_in, const int* in_sizes, int n_in,
                              void* d_out, int out_size, void* d_ws, size_t ws_size,
                              hipStream_t stream) {
    const float* preds = (const float*)d_in[0];
    const int* targets = (const int*)d_in[1];
    int batch = in_sizes[1];  // 4194304 rows
    unsigned int* partial = (unsigned int*)d_ws;

    path_loss_partial<<<GRID, BLOCK, 0, stream>>>(preds, targets, partial, batch);
    path_loss_final<<<1, 1024, 0, stream>>>(partial, (float*)d_out, batch);
}